// Round 14
// baseline (101.194 us; speedup 1.0000x reference)
//
#include <hip/hip_runtime.h>
#include <math.h>

#define NB 32
#define NT 512
#define NS 64
#define NOBS 4
#define NEMB 32
#define NPE 16
#define NATTN 10
#define ND 26  // ATTN + PE

typedef _Float16 half2_t __attribute__((ext_vector_type(2)));

// obs_emb_weights LDS layout: 64 rows (sensor s) x 128 dwords (o*32+e),
// 16B-chunk XOR swizzle so per-lane ds_read_b128 of row s spreads banks.
__device__ __forceinline__ int obs_idx(int s, int chunk) {
    return (s << 7) + (((chunk ^ (s & 7)) & 31) << 2);
}

// pack two f32 -> one dword of two f16 (scalar cvt; proven R7/R13 path)
__device__ __forceinline__ unsigned pkh(float a, float b) {
    _Float16 ha = (_Float16)a, hb = (_Float16)b;
    unsigned short ua, ub;
    __builtin_memcpy(&ua, &ha, 2);
    __builtin_memcpy(&ub, &hb, 2);
    return (unsigned)ua | ((unsigned)ub << 16);
}

__device__ __forceinline__ float2 unpack_h2(unsigned u) {
    unsigned short l16 = (unsigned short)(u & 0xffffu);
    unsigned short h16 = (unsigned short)(u >> 16);
    _Float16 lo, hi;
    __builtin_memcpy(&lo, &l16, 2);
    __builtin_memcpy(&hi, &h16, 2);
    return make_float2((float)lo, (float)hi);
}

// c += dot2(packed f16 a, packed f16 b): one v_dot2_f32_f16
__device__ __forceinline__ float dot2h(unsigned a, unsigned b, float c) {
#if __has_builtin(__builtin_amdgcn_fdot2)
    return __builtin_amdgcn_fdot2(__builtin_bit_cast(half2_t, a),
                                  __builtin_bit_cast(half2_t, b), c, false);
#else
    float2 fa = unpack_h2(a), fb = unpack_h2(b);
    return c + fa.x * fb.x + fa.y * fb.y;
#endif
}

__global__ __launch_bounds__(512)
void raindrop_kernel(const float* __restrict__ x,
                     const float* __restrict__ times,
                     const float* __restrict__ mask,
                     const float* __restrict__ obsW,
                     const float* __restrict__ attnW,
                     const float* __restrict__ recvW,
                     const float* __restrict__ recvB,
                     float* __restrict__ out)
{
    // 33 KiB total -> 4 blocks/CU, 32 waves/CU (R8 occupancy). lds reused:
    // phase 1 = swizzled f32 obsW tile; phase 3 = packed-f16 hq rows (16 KiB).
    __shared__ float lds[NS * 128];
    __shared__ float wpe[8 * NEMB];  // 1 KiB per-wave folded-PE strips

    const int tid = threadIdx.x;

    // Stage S*OBS*EMB = 8192 floats (coalesced float4 reads, swizzled writes)
#pragma unroll
    for (int k = 0; k < 4; ++k) {
        int i = (tid << 2) + (k << 11);
        float4 v = *reinterpret_cast<const float4*>(obsW + i);
        *reinterpret_cast<float4*>(&lds[obs_idx(i >> 7, (i & 127) >> 2)]) = v;
    }

    const int lane = tid & 63;
    const int wv = tid >> 6;
    const int bt = blockIdx.x * 8 + wv;   // one wave per (b,t)
    const int s = lane;                   // phase-1 role: lane = sensor
    const int g = lane >> 3;              // phase-3: 8 row-groups
    const int iu = lane & 7;              // phase-3: u-octet owner (u=iu*8+j)

    // per-lane attnW octet, PACKED f16: 8 u x 5 dwords = 40 VGPRs
    // (same register cost as R8's 40-f32 quad -> no R11 VGPR cliff).
    unsigned awp[8][5];
    {
        const float2* ap = reinterpret_cast<const float2*>(attnW + (iu * 8) * NATTN);
#pragma unroll
        for (int j = 0; j < 8; ++j)
#pragma unroll
            for (int q = 0; q < 5; ++q) {
                float2 v = ap[j * 5 + q];
                awp[j][q] = pkh(v.x, v.y);
            }
    }

    // positional encoding (wave-uniform; div[i] = 10^(-i/2)); native sin/cos
    const float tt = times[bt];
    const float divs[8] = {1.0f, 0.31622776601683794f, 0.1f, 0.031622776601683794f,
                           0.01f, 0.0031622776601683794f, 0.001f, 0.00031622776601683794f};
    float pe[NPE];
#pragma unroll
    for (int i = 0; i < 8; ++i) {
        float ang = tt * divs[i];
        pe[2 * i]     = __sinf(ang);
        pe[2 * i + 1] = __cosf(ang);
    }

    // c0 = recvB[10:26] . pe  (uniform; recvB via s_load)
    float c0 = 0.f;
#pragma unroll
    for (int p = 0; p < NPE; ++p) c0 += recvB[NATTN + p] * pe[p];

    // w_pe: lane e (= lane&31) folds recvW[e][10..25] with pe -> LDS strip.
    float* wpw = &wpe[wv * NEMB];
    {
        const int e = lane & 31;
        const float2* rp = reinterpret_cast<const float2*>(recvW + e * ND + NATTN);
        float acc = 0.f;
#pragma unroll
        for (int p2 = 0; p2 < 8; ++p2) {
            float2 w = rp[p2];
            acc += w.x * pe[2 * p2];
            acc += w.y * pe[2 * p2 + 1];
        }
        if (lane < NEMB) wpw[e] = acc;
    }

    // per-lane inputs (coalesced: 64 lanes x 16B contiguous)
    const float4 xv = *reinterpret_cast<const float4*>(x + ((size_t)bt * NS + s) * NOBS);
    const float  mv = mask[(size_t)bt * NS + s];

    __syncthreads();  // obsW tile + wpe ready

    // hq[a] = recv_b[a] + sum_e h_e * recv_W[e][a]   (a = 0..9 only)
    // beta' = sum_e h_e * w_pe[e]      (f32 phase 1, byte-identical to R8)
    float hq[NATTN];
#pragma unroll
    for (int a = 0; a < NATTN; ++a) hq[a] = recvB[a];  // uniform -> s_load
    float betah = 0.f;

#pragma unroll
    for (int eb = 0; eb < 8; ++eb) {  // e = eb*4 + j
        float a0 = 0.f, a1 = 0.f, a2 = 0.f, a3 = 0.f;
        {
            float4 w0 = *reinterpret_cast<const float4*>(&lds[obs_idx(s, 0 * 8 + eb)]);
            a0 += xv.x * w0.x; a1 += xv.x * w0.y; a2 += xv.x * w0.z; a3 += xv.x * w0.w;
            float4 w1 = *reinterpret_cast<const float4*>(&lds[obs_idx(s, 1 * 8 + eb)]);
            a0 += xv.y * w1.x; a1 += xv.y * w1.y; a2 += xv.y * w1.z; a3 += xv.y * w1.w;
            float4 w2 = *reinterpret_cast<const float4*>(&lds[obs_idx(s, 2 * 8 + eb)]);
            a0 += xv.z * w2.x; a1 += xv.z * w2.y; a2 += xv.z * w2.z; a3 += xv.z * w2.w;
            float4 w3 = *reinterpret_cast<const float4*>(&lds[obs_idx(s, 3 * 8 + eb)]);
            a0 += xv.w * w3.x; a1 += xv.w * w3.y; a2 += xv.w * w3.z; a3 += xv.w * w3.w;
        }
        const float h0 = fmaxf(a0, 0.f) * mv;
        const float h1 = fmaxf(a1, 0.f) * mv;
        const float h2 = fmaxf(a2, 0.f) * mv;
        const float h3 = fmaxf(a3, 0.f) * mv;

        // beta' contribution: uniform ds_read_b128 broadcast of 4 w_pe
        float4 wp = *reinterpret_cast<const float4*>(wpw + eb * 4);
        betah += h0 * wp.x + h1 * wp.y + h2 * wp.z + h3 * wp.w;

        const float* rw = recvW + (eb * 4) * ND;  // uniform base -> s_load
#pragma unroll
        for (int a = 0; a < NATTN; ++a) {
            hq[a] += h0 * rw[a] + h1 * rw[ND + a] + h2 * rw[2 * ND + a] + h3 * rw[3 * ND + a];
        }
    }

    const float beta = c0 + betah;

    __syncthreads();  // all waves done READING the obsW tile -> safe to reuse

    // Stage this wave's hq row PACKED f16 (+f32 beta), 8-dword (32B) stride.
    // Write: 64 lanes x 32B stride -> 8-way bank alias on 2 instrs (negligible).
    unsigned* hbase = reinterpret_cast<unsigned*>(&lds[0]) + wv * (NS * 8);
    {
        unsigned* hrow = hbase + s * 8;
        uint4 rA;
        rA.x = pkh(hq[0], hq[1]); rA.y = pkh(hq[2], hq[3]);
        rA.z = pkh(hq[4], hq[5]); rA.w = pkh(hq[6], hq[7]);
        uint2 rB;
        rB.x = pkh(hq[8], hq[9]);
        rB.y = __builtin_bit_cast(unsigned, beta);
        *reinterpret_cast<uint4*>(hrow)     = rA;
        *reinterpret_cast<uint2*>(hrow + 4) = rB;
    }
    // No barrier: same-wave write->read (in-order DS, proven R5-R13).

    // Phase 3: 8 row-groups x 8 lanes. Per iter: b128+b64 at 8 distinct
    // 32B-strided addrs (2-way bank alias = free, m136), broadcast within
    // 8-lane groups; 40 fdot2 + 8 fmax per lane (one fdot2 = 2 FMA, packed
    // operands -> zero unpack); two float4 stores (8 rows x 256B per iter).
    const unsigned* hg = hbase + g * 8;
    float* optr = out + (size_t)bt * (NS * NS) + g * NS + iu * 8;
#pragma unroll 2
    for (int r = 0; r < NS; r += 8) {
        const unsigned* hr = hg + r * 8;
        uint4 A = *reinterpret_cast<const uint4*>(hr);
        uint2 Bv = *reinterpret_cast<const uint2*>(hr + 4);
        const float beta_r = __builtin_bit_cast(float, Bv.y);
        float res[8];
#pragma unroll
        for (int j = 0; j < 8; ++j) {
            float acc = beta_r;
            acc = dot2h(A.x, awp[j][0], acc);
            acc = dot2h(A.y, awp[j][1], acc);
            acc = dot2h(A.z, awp[j][2], acc);
            acc = dot2h(A.w, awp[j][3], acc);
            acc = dot2h(Bv.x, awp[j][4], acc);
            res[j] = fmaxf(acc, 0.f);
        }
        float4 rv0 = {res[0], res[1], res[2], res[3]};
        float4 rv1 = {res[4], res[5], res[6], res[7]};
        *reinterpret_cast<float4*>(optr)     = rv0;  // u = iu*8 .. +3
        *reinterpret_cast<float4*>(optr + 4) = rv1;  // u = iu*8+4 .. +7
        optr += 8 * NS;
    }
}

extern "C" void kernel_launch(void* const* d_in, const int* in_sizes, int n_in,
                              void* d_out, int out_size, void* d_ws, size_t ws_size,
                              hipStream_t stream) {
    const float* x     = (const float*)d_in[0];
    const float* times = (const float*)d_in[1];
    const float* mask  = (const float*)d_in[2];
    const float* obsW  = (const float*)d_in[3];
    const float* attnW = (const float*)d_in[4];
    const float* recvW = (const float*)d_in[5];
    const float* recvB = (const float*)d_in[6];
    float* out = (float*)d_out;

    // B*T = 16384 (b,t) pairs, one wave each, 8 waves per block
    raindrop_kernel<<<dim3((NB * NT) / 8), dim3(512), 0, stream>>>(
        x, times, mask, obsW, attnW, recvW, recvB, out);
}

// Round 16
// 62.409 us; speedup vs baseline: 1.6215x; 1.6215x over previous
//
#include <hip/hip_runtime.h>
#include <math.h>

#define NB 32
#define NT 512
#define NS 64
#define NOBS 4
#define NEMB 32
#define NPE 16
#define NATTN 10
#define ND 26  // ATTN + PE

typedef float f32x4 __attribute__((ext_vector_type(4)));  // native vec for nt-store

// obs_emb_weights LDS layout: 64 rows (sensor s) x 128 dwords (o*32+e),
// 16B-chunk XOR swizzle so per-lane ds_read_b128 of row s spreads banks.
__device__ __forceinline__ int obs_idx(int s, int chunk) {
    return (s << 7) + (((chunk ^ (s & 7)) & 31) << 2);
}

__global__ __launch_bounds__(512)
void raindrop_kernel(const float* __restrict__ x,
                     const float* __restrict__ times,
                     const float* __restrict__ mask,
                     const float* __restrict__ obsW,
                     const float* __restrict__ attnW,
                     const float* __restrict__ recvW,
                     const float* __restrict__ recvB,
                     float* __restrict__ out)
{
    // 33 KiB total -> 4 blocks/CU, 32 waves/CU. lds reused: phase 1 =
    // swizzled obsW tile; phase 3 = hq rows (proven R8 structure).
    __shared__ float lds[NS * 128];
    __shared__ float wpe[8 * NEMB];  // 1 KiB per-wave folded-PE strips

    const int tid = threadIdx.x;

    // Stage S*OBS*EMB = 8192 floats into LDS (coalesced global float4 reads,
    // swizzled LDS writes). 512 threads x 4 iters x 4 floats.
#pragma unroll
    for (int k = 0; k < 4; ++k) {
        int i = (tid << 2) + (k << 11);
        float4 v = *reinterpret_cast<const float4*>(obsW + i);
        *reinterpret_cast<float4*>(&lds[obs_idx(i >> 7, (i & 127) >> 2)]) = v;
    }

    const int lane = tid & 63;
    const int wv = tid >> 6;
    const int bt = blockIdx.x * 8 + wv;   // one wave per (b,t)
    const int s = lane;                   // phase-1 role: lane = sensor
    const int g = lane >> 4;              // phase-3 row group
    const int iu = lane & 15;             // phase-3 u-quad owner

    // per-lane attnW quad for phase 3 (40 f32 VGPRs — R8-proven budget)
    float aw0[NATTN], aw1[NATTN], aw2[NATTN], aw3[NATTN];
    {
        const float2* ap = reinterpret_cast<const float2*>(attnW + (iu * 4) * NATTN);
#pragma unroll
        for (int q = 0; q < 5; ++q) {
            float2 v0 = ap[q];      aw0[2*q] = v0.x; aw0[2*q+1] = v0.y;
            float2 v1 = ap[5 + q];  aw1[2*q] = v1.x; aw1[2*q+1] = v1.y;
            float2 v2 = ap[10 + q]; aw2[2*q] = v2.x; aw2[2*q+1] = v2.y;
            float2 v3 = ap[15 + q]; aw3[2*q] = v3.x; aw3[2*q+1] = v3.y;
        }
    }

    // positional encoding (wave-uniform; div[i] = 10^(-i/2)); native sin/cos
    const float tt = times[bt];
    const float divs[8] = {1.0f, 0.31622776601683794f, 0.1f, 0.031622776601683794f,
                           0.01f, 0.0031622776601683794f, 0.001f, 0.00031622776601683794f};
    float pe[NPE];
#pragma unroll
    for (int i = 0; i < 8; ++i) {
        float ang = tt * divs[i];
        pe[2 * i]     = __sinf(ang);
        pe[2 * i + 1] = __cosf(ang);
    }

    // c0 = recvB[10:26] . pe  (uniform; recvB via s_load)
    float c0 = 0.f;
#pragma unroll
    for (int p = 0; p < NPE; ++p) c0 += recvB[NATTN + p] * pe[p];

    // w_pe: lane e (= lane&31) folds recvW[e][10..25] with pe -> LDS strip.
    float* wpw = &wpe[wv * NEMB];
    {
        const int e = lane & 31;
        const float2* rp = reinterpret_cast<const float2*>(recvW + e * ND + NATTN);
        float acc = 0.f;
#pragma unroll
        for (int p2 = 0; p2 < 8; ++p2) {
            float2 w = rp[p2];
            acc += w.x * pe[2 * p2];
            acc += w.y * pe[2 * p2 + 1];
        }
        if (lane < NEMB) wpw[e] = acc;
    }

    // per-lane inputs (coalesced: 64 lanes x 16B contiguous)
    const float4 xv = *reinterpret_cast<const float4*>(x + ((size_t)bt * NS + s) * NOBS);
    const float  mv = mask[(size_t)bt * NS + s];

    __syncthreads();  // obsW tile + wpe ready

    // hq[a] = recv_b[a] + sum_e h_e * recv_W[e][a]   (a = 0..9 only)
    // beta' = sum_e h_e * w_pe[e]
    float hq[NATTN];
#pragma unroll
    for (int a = 0; a < NATTN; ++a) hq[a] = recvB[a];  // uniform -> s_load
    float betah = 0.f;

#pragma unroll
    for (int eb = 0; eb < 8; ++eb) {  // e = eb*4 + j
        float a0 = 0.f, a1 = 0.f, a2 = 0.f, a3 = 0.f;
        {
            float4 w0 = *reinterpret_cast<const float4*>(&lds[obs_idx(s, 0 * 8 + eb)]);
            a0 += xv.x * w0.x; a1 += xv.x * w0.y; a2 += xv.x * w0.z; a3 += xv.x * w0.w;
            float4 w1 = *reinterpret_cast<const float4*>(&lds[obs_idx(s, 1 * 8 + eb)]);
            a0 += xv.y * w1.x; a1 += xv.y * w1.y; a2 += xv.y * w1.z; a3 += xv.y * w1.w;
            float4 w2 = *reinterpret_cast<const float4*>(&lds[obs_idx(s, 2 * 8 + eb)]);
            a0 += xv.z * w2.x; a1 += xv.z * w2.y; a2 += xv.z * w2.z; a3 += xv.z * w2.w;
            float4 w3 = *reinterpret_cast<const float4*>(&lds[obs_idx(s, 3 * 8 + eb)]);
            a0 += xv.w * w3.x; a1 += xv.w * w3.y; a2 += xv.w * w3.z; a3 += xv.w * w3.w;
        }
        const float h0 = fmaxf(a0, 0.f) * mv;
        const float h1 = fmaxf(a1, 0.f) * mv;
        const float h2 = fmaxf(a2, 0.f) * mv;
        const float h3 = fmaxf(a3, 0.f) * mv;

        // beta' contribution: uniform ds_read_b128 broadcast of 4 w_pe
        float4 wp = *reinterpret_cast<const float4*>(wpw + eb * 4);
        betah += h0 * wp.x + h1 * wp.y + h2 * wp.z + h3 * wp.w;

        const float* rw = recvW + (eb * 4) * ND;  // uniform base -> s_load
#pragma unroll
        for (int a = 0; a < NATTN; ++a) {
            hq[a] += h0 * rw[a] + h1 * rw[ND + a] + h2 * rw[2 * ND + a] + h3 * rw[3 * ND + a];
        }
    }

    const float beta = c0 + betah;

    __syncthreads();  // all waves done READING the obsW tile -> safe to reuse

    // Stage this wave's hq rows (wave-private region, 64 rows x 12 floats).
    float* hbase = &lds[wv * (NS * 12)];
    {
        float* hrow = hbase + s * 12;
        float4 v0 = {hq[0], hq[1], hq[2], hq[3]};
        float4 v1 = {hq[4], hq[5], hq[6], hq[7]};
        float4 v2 = {hq[8], hq[9], beta, 0.f};
        *reinterpret_cast<float4*>(hrow)     = v0;
        *reinterpret_cast<float4*>(hrow + 4) = v1;
        *reinterpret_cast<float4*>(hrow + 8) = v2;
    }
    // No barrier: this wave reads only rows its own lanes wrote, and DS ops
    // from one wave complete in program order.

    // Phase 3 (R8-proven): 4 row-groups x 16 lanes; 3 ds_read_b128 per iter
    // at 4 distinct 48B-strided addrs (disjoint bank quads, conflict-free),
    // 40 FMA/lane, one coalesced 1KB wave store — NONTEMPORAL (native
    // ext_vector_type; HIP float4 class is rejected by the builtin).
    const float* hgbase = hbase + g * 12;
    float* optr = out + (size_t)bt * (NS * NS) + g * NS + iu * 4;
#pragma unroll 4
    for (int r = 0; r < NS; r += 4) {
        const float* hr = hgbase + r * 12;
        float4 h0 = *reinterpret_cast<const float4*>(hr);
        float4 h1 = *reinterpret_cast<const float4*>(hr + 4);
        float4 h2 = *reinterpret_cast<const float4*>(hr + 8);
        float acc0 = h2.z, acc1 = h2.z, acc2 = h2.z, acc3 = h2.z;  // beta_r
        acc0 += h0.x * aw0[0]; acc1 += h0.x * aw1[0]; acc2 += h0.x * aw2[0]; acc3 += h0.x * aw3[0];
        acc0 += h0.y * aw0[1]; acc1 += h0.y * aw1[1]; acc2 += h0.y * aw2[1]; acc3 += h0.y * aw3[1];
        acc0 += h0.z * aw0[2]; acc1 += h0.z * aw1[2]; acc2 += h0.z * aw2[2]; acc3 += h0.z * aw3[2];
        acc0 += h0.w * aw0[3]; acc1 += h0.w * aw1[3]; acc2 += h0.w * aw2[3]; acc3 += h0.w * aw3[3];
        acc0 += h1.x * aw0[4]; acc1 += h1.x * aw1[4]; acc2 += h1.x * aw2[4]; acc3 += h1.x * aw3[4];
        acc0 += h1.y * aw0[5]; acc1 += h1.y * aw1[5]; acc2 += h1.y * aw2[5]; acc3 += h1.y * aw3[5];
        acc0 += h1.z * aw0[6]; acc1 += h1.z * aw1[6]; acc2 += h1.z * aw2[6]; acc3 += h1.z * aw3[6];
        acc0 += h1.w * aw0[7]; acc1 += h1.w * aw1[7]; acc2 += h1.w * aw2[7]; acc3 += h1.w * aw3[7];
        acc0 += h2.x * aw0[8]; acc1 += h2.x * aw1[8]; acc2 += h2.x * aw2[8]; acc3 += h2.x * aw3[8];
        acc0 += h2.y * aw0[9]; acc1 += h2.y * aw1[9]; acc2 += h2.y * aw2[9]; acc3 += h2.y * aw3[9];
        f32x4 rv;
        rv.x = fmaxf(acc0, 0.f);
        rv.y = fmaxf(acc1, 0.f);
        rv.z = fmaxf(acc2, 0.f);
        rv.w = fmaxf(acc3, 0.f);
        __builtin_nontemporal_store(rv, reinterpret_cast<f32x4*>(optr));
        optr += 4 * NS;
    }
}

extern "C" void kernel_launch(void* const* d_in, const int* in_sizes, int n_in,
                              void* d_out, int out_size, void* d_ws, size_t ws_size,
                              hipStream_t stream) {
    const float* x     = (const float*)d_in[0];
    const float* times = (const float*)d_in[1];
    const float* mask  = (const float*)d_in[2];
    const float* obsW  = (const float*)d_in[3];
    const float* attnW = (const float*)d_in[4];
    const float* recvW = (const float*)d_in[5];
    const float* recvB = (const float*)d_in[6];
    float* out = (float*)d_out;

    // B*T = 16384 (b,t) pairs, one wave each, 8 waves per block
    raindrop_kernel<<<dim3((NB * NT) / 8), dim3(512), 0, stream>>>(
        x, times, mask, obsW, attnW, recvW, recvB, out);
}

// Round 17
// 56.988 us; speedup vs baseline: 1.7757x; 1.0951x over previous
//
#include <hip/hip_runtime.h>
#include <math.h>

#define NB 32
#define NT 512
#define NS 64
#define NOBS 4
#define NEMB 32
#define NPE 16
#define NATTN 10
#define ND 26  // ATTN + PE

typedef float f32x4 __attribute__((ext_vector_type(4)));  // native vec for nt-store
typedef float f32x2 __attribute__((ext_vector_type(2)));  // v_pk_*_f32 carrier

// obs_emb_weights LDS layout: 64 rows (sensor s) x 128 dwords (o*32+e),
// 16B-chunk XOR swizzle so per-lane ds_read_b128 of row s spreads banks.
__device__ __forceinline__ int obs_idx(int s, int chunk) {
    return (s << 7) + (((chunk ^ (s & 7)) & 31) << 2);
}

__global__ __launch_bounds__(512)
void raindrop_kernel(const float* __restrict__ x,
                     const float* __restrict__ times,
                     const float* __restrict__ mask,
                     const float* __restrict__ obsW,
                     const float* __restrict__ attnW,
                     const float* __restrict__ recvW,
                     const float* __restrict__ recvB,
                     float* __restrict__ out)
{
    // 33 KiB total -> 4 blocks/CU, 32 waves/CU. lds reused: phase 1 =
    // swizzled obsW tile; phase 3 = hq rows (R8/R16-proven structure).
    __shared__ float lds[NS * 128];
    __shared__ float wpe[8 * NEMB];  // 1 KiB per-wave folded-PE strips

    const int tid = threadIdx.x;

    // Stage S*OBS*EMB = 8192 floats into LDS (coalesced global float4 reads,
    // swizzled LDS writes). 512 threads x 4 iters x 4 floats.
#pragma unroll
    for (int k = 0; k < 4; ++k) {
        int i = (tid << 2) + (k << 11);
        float4 v = *reinterpret_cast<const float4*>(obsW + i);
        *reinterpret_cast<float4*>(&lds[obs_idx(i >> 7, (i & 127) >> 2)]) = v;
    }

    const int lane = tid & 63;
    const int wv = tid >> 6;
    const int bt = blockIdx.x * 8 + wv;   // one wave per (b,t)
    const int s = lane;                   // phase-1 role: lane = sensor
    const int g = lane >> 4;              // phase-3 row group
    const int iu = lane & 15;             // phase-3 u-quad owner

    // per-lane attnW quad for phase 3, pre-transposed into u-PAIRS:
    // awA[q] = {aw_u0[q], aw_u1[q]}, awB[q] = {aw_u2[q], aw_u3[q]}.
    // Same 40 VGPRs as R16 (no R11 cliff); enables v_pk_fma in phase 3.
    f32x2 awA[NATTN], awB[NATTN];
    {
        const float2* ap = reinterpret_cast<const float2*>(attnW + (iu * 4) * NATTN);
        float a0[NATTN], a1[NATTN], a2[NATTN], a3[NATTN];
#pragma unroll
        for (int q = 0; q < 5; ++q) {
            float2 v0 = ap[q];      a0[2*q] = v0.x; a0[2*q+1] = v0.y;
            float2 v1 = ap[5 + q];  a1[2*q] = v1.x; a1[2*q+1] = v1.y;
            float2 v2 = ap[10 + q]; a2[2*q] = v2.x; a2[2*q+1] = v2.y;
            float2 v3 = ap[15 + q]; a3[2*q] = v3.x; a3[2*q+1] = v3.y;
        }
#pragma unroll
        for (int q = 0; q < NATTN; ++q) {
            awA[q] = (f32x2){a0[q], a1[q]};
            awB[q] = (f32x2){a2[q], a3[q]};
        }
    }

    // positional encoding (wave-uniform; div[i] = 10^(-i/2)); native sin/cos
    const float tt = times[bt];
    const float divs[8] = {1.0f, 0.31622776601683794f, 0.1f, 0.031622776601683794f,
                           0.01f, 0.0031622776601683794f, 0.001f, 0.00031622776601683794f};
    float pe[NPE];
#pragma unroll
    for (int i = 0; i < 8; ++i) {
        float ang = tt * divs[i];
        pe[2 * i]     = __sinf(ang);
        pe[2 * i + 1] = __cosf(ang);
    }

    // c0 = recvB[10:26] . pe  (uniform; recvB via s_load)
    float c0 = 0.f;
#pragma unroll
    for (int p = 0; p < NPE; ++p) c0 += recvB[NATTN + p] * pe[p];

    // w_pe: lane e (= lane&31) folds recvW[e][10..25] with pe -> LDS strip.
    float* wpw = &wpe[wv * NEMB];
    {
        const int e = lane & 31;
        const float2* rp = reinterpret_cast<const float2*>(recvW + e * ND + NATTN);
        float acc = 0.f;
#pragma unroll
        for (int p2 = 0; p2 < 8; ++p2) {
            float2 w = rp[p2];
            acc += w.x * pe[2 * p2];
            acc += w.y * pe[2 * p2 + 1];
        }
        if (lane < NEMB) wpw[e] = acc;
    }

    // per-lane inputs (coalesced: 64 lanes x 16B contiguous)
    const float4 xv = *reinterpret_cast<const float4*>(x + ((size_t)bt * NS + s) * NOBS);
    const float  mv = mask[(size_t)bt * NS + s];

    __syncthreads();  // obsW tile + wpe ready

    // hq[a] = recv_b[a] + sum_e h_e * recv_W[e][a]  (a = 0..9, as 5 pairs)
    // beta' = sum_e h_e * w_pe[e]                   (pair-accumulated)
    // All inner math packed f32x2 -> v_pk_fma_f32 (2 FMA/instr).
    const f32x2 zero2 = {0.f, 0.f};
    const f32x2 mv2 = {mv, mv};

    f32x2 hq2[5];
    {
        const f32x2* rb2 = reinterpret_cast<const f32x2*>(recvB);  // 8B-aligned
#pragma unroll
        for (int p = 0; p < 5; ++p) hq2[p] = rb2[p];  // uniform -> s_load
    }
    f32x2 beta2 = zero2;

#pragma unroll
    for (int eb = 0; eb < 8; ++eb) {  // e = eb*4 + j
        f32x2 p01 = zero2, p23 = zero2;
        {
            float4 w0 = *reinterpret_cast<const float4*>(&lds[obs_idx(s, 0 * 8 + eb)]);
            f32x2 xx = {xv.x, xv.x};
            p01 += xx * (f32x2){w0.x, w0.y};
            p23 += xx * (f32x2){w0.z, w0.w};
            float4 w1 = *reinterpret_cast<const float4*>(&lds[obs_idx(s, 1 * 8 + eb)]);
            f32x2 xy = {xv.y, xv.y};
            p01 += xy * (f32x2){w1.x, w1.y};
            p23 += xy * (f32x2){w1.z, w1.w};
            float4 w2 = *reinterpret_cast<const float4*>(&lds[obs_idx(s, 2 * 8 + eb)]);
            f32x2 xz = {xv.z, xv.z};
            p01 += xz * (f32x2){w2.x, w2.y};
            p23 += xz * (f32x2){w2.z, w2.w};
            float4 w3 = *reinterpret_cast<const float4*>(&lds[obs_idx(s, 3 * 8 + eb)]);
            f32x2 xw = {xv.w, xv.w};
            p01 += xw * (f32x2){w3.x, w3.y};
            p23 += xw * (f32x2){w3.z, w3.w};
        }
        const f32x2 h01 = __builtin_elementwise_max(p01, zero2) * mv2;
        const f32x2 h23 = __builtin_elementwise_max(p23, zero2) * mv2;

        // beta' contribution: uniform ds_read_b128 broadcast of 4 w_pe
        float4 wp = *reinterpret_cast<const float4*>(wpw + eb * 4);
        beta2 += h01 * (f32x2){wp.x, wp.y};
        beta2 += h23 * (f32x2){wp.z, wp.w};

        // hq pairs: 4 e-rows of recvW[.][0..9] as 5 f32x2 each (8B-aligned:
        // e*26 floats is even). Uniform base -> s_load; 20 pk-FMA per eb.
        const f32x2 h0v = {h01.x, h01.x};
        const f32x2 h1v = {h01.y, h01.y};
        const f32x2 h2v = {h23.x, h23.x};
        const f32x2 h3v = {h23.y, h23.y};
        const f32x2* r0 = reinterpret_cast<const f32x2*>(recvW + (eb * 4 + 0) * ND);
        const f32x2* r1 = reinterpret_cast<const f32x2*>(recvW + (eb * 4 + 1) * ND);
        const f32x2* r2 = reinterpret_cast<const f32x2*>(recvW + (eb * 4 + 2) * ND);
        const f32x2* r3 = reinterpret_cast<const f32x2*>(recvW + (eb * 4 + 3) * ND);
#pragma unroll
        for (int p = 0; p < 5; ++p) {
            hq2[p] += h0v * r0[p] + h1v * r1[p] + h2v * r2[p] + h3v * r3[p];
        }
    }

    const float beta = c0 + beta2.x + beta2.y;

    __syncthreads();  // all waves done READING the obsW tile -> safe to reuse

    // Stage this wave's hq rows (wave-private region, 64 rows x 12 floats).
    float* hbase = &lds[wv * (NS * 12)];
    {
        float* hrow = hbase + s * 12;
        float4 v0 = {hq2[0].x, hq2[0].y, hq2[1].x, hq2[1].y};
        float4 v1 = {hq2[2].x, hq2[2].y, hq2[3].x, hq2[3].y};
        float4 v2 = {hq2[4].x, hq2[4].y, beta, 0.f};
        *reinterpret_cast<float4*>(hrow)     = v0;
        *reinterpret_cast<float4*>(hrow + 4) = v1;
        *reinterpret_cast<float4*>(hrow + 8) = v2;
    }
    // No barrier: this wave reads only rows its own lanes wrote, and DS ops
    // from one wave complete in program order.

    // Phase 3 (R8/R16 memory structure): 4 row-groups x 16 lanes; 3
    // ds_read_b128 per iter at 4 distinct 48B-strided addrs (disjoint bank
    // quads, conflict-free); 20 pk-FMA + 2 pk-max per lane; one coalesced
    // 1KB wave store — NONTEMPORAL (proven R16, -3.4us).
    const float* hgbase = hbase + g * 12;
    float* optr = out + (size_t)bt * (NS * NS) + g * NS + iu * 4;
#pragma unroll 4
    for (int r = 0; r < NS; r += 4) {
        const float* hr = hgbase + r * 12;
        float4 h0 = *reinterpret_cast<const float4*>(hr);
        float4 h1 = *reinterpret_cast<const float4*>(hr + 4);
        float4 h2 = *reinterpret_cast<const float4*>(hr + 8);
        f32x2 accA = {h2.z, h2.z};  // beta_r pair (u0,u1)
        f32x2 accB = {h2.z, h2.z};  // beta_r pair (u2,u3)
        f32x2 q;
        q = (f32x2){h0.x, h0.x}; accA += q * awA[0]; accB += q * awB[0];
        q = (f32x2){h0.y, h0.y}; accA += q * awA[1]; accB += q * awB[1];
        q = (f32x2){h0.z, h0.z}; accA += q * awA[2]; accB += q * awB[2];
        q = (f32x2){h0.w, h0.w}; accA += q * awA[3]; accB += q * awB[3];
        q = (f32x2){h1.x, h1.x}; accA += q * awA[4]; accB += q * awB[4];
        q = (f32x2){h1.y, h1.y}; accA += q * awA[5]; accB += q * awB[5];
        q = (f32x2){h1.z, h1.z}; accA += q * awA[6]; accB += q * awB[6];
        q = (f32x2){h1.w, h1.w}; accA += q * awA[7]; accB += q * awB[7];
        q = (f32x2){h2.x, h2.x}; accA += q * awA[8]; accB += q * awB[8];
        q = (f32x2){h2.y, h2.y}; accA += q * awA[9]; accB += q * awB[9];
        accA = __builtin_elementwise_max(accA, (f32x2){0.f, 0.f});
        accB = __builtin_elementwise_max(accB, (f32x2){0.f, 0.f});
        f32x4 rv;
        rv.x = accA.x; rv.y = accA.y; rv.z = accB.x; rv.w = accB.y;
        __builtin_nontemporal_store(rv, reinterpret_cast<f32x4*>(optr));
        optr += 4 * NS;
    }
}

extern "C" void kernel_launch(void* const* d_in, const int* in_sizes, int n_in,
                              void* d_out, int out_size, void* d_ws, size_t ws_size,
                              hipStream_t stream) {
    const float* x     = (const float*)d_in[0];
    const float* times = (const float*)d_in[1];
    const float* mask  = (const float*)d_in[2];
    const float* obsW  = (const float*)d_in[3];
    const float* attnW = (const float*)d_in[4];
    const float* recvW = (const float*)d_in[5];
    const float* recvB = (const float*)d_in[6];
    float* out = (float*)d_out;

    // B*T = 16384 (b,t) pairs, one wave each, 8 waves per block
    raindrop_kernel<<<dim3((NB * NT) / 8), dim3(512), 0, stream>>>(
        x, times, mask, obsW, attnW, recvW, recvB, out);
}